// Round 15
// baseline (595.744 us; speedup 1.0000x reference)
//
#include <hip/hip_runtime.h>
#include <hip/hip_bf16.h>
#include <cstdint>
#include <cstddef>

// Problem constants
constexpr int Bc  = 4;
constexpr int Sc  = 2048;
constexpr int DMc = 1024;   // d_model
constexpr int Hc  = 16;     // heads
constexpr int DHc = 64;     // head dim
constexpr int BHc = Bc * Hc;

typedef float f32x4  __attribute__((ext_vector_type(4)));
typedef short bf16x8 __attribute__((ext_vector_type(8)));

// f32 -> bf16 (RNE), scalar fallback
static __device__ __forceinline__ short f2bf(float x) {
  uint32_t u = __builtin_bit_cast(uint32_t, x);
  u += 0x7fffu + ((u >> 16) & 1u);
  return (short)(u >> 16);
}

// 2x f32 -> packed 2x bf16 (RNE) via v_cvt_pk_bf16_f32 (1 VALU op)
static __device__ __forceinline__ uint32_t pk2bf(float a, float b) {
  __hip_bfloat162 h = __float22bfloat162_rn(float2{a, b});
  uint32_t r;
  __builtin_memcpy(&r, &h, 4);
  return r;
}

static __device__ __forceinline__ f32x4 mfma16(bf16x8 a, bf16x8 b, f32x4 c) {
  return __builtin_amdgcn_mfma_f32_16x16x32_bf16(a, b, c, 0, 0, 0);
}

// async global->LDS, 16B per lane. LDS dest is wave-uniform base + lane*16.
static __device__ __forceinline__ void gload16(const short* g, short* l) {
  __builtin_amdgcn_global_load_lds(
      (const __attribute__((address_space(1))) void*)g,
      (__attribute__((address_space(3))) void*)l, 16, 0, 0);
}

// ---------------- all f32->bf16 conversions in ONE launch ----------------
__global__ __launch_bounds__(256) void k_cvtall(const float* __restrict__ iQ,
                                                const float* __restrict__ iK,
                                                const float* __restrict__ iV,
                                                const float* __restrict__ wQ,
                                                const float* __restrict__ wK,
                                                const float* __restrict__ wV,
                                                const float* __restrict__ wO,
                                                short* __restrict__ oQ,
                                                short* __restrict__ oK,
                                                short* __restrict__ oV,
                                                short* __restrict__ owQ,
                                                short* __restrict__ owK,
                                                short* __restrict__ owV,
                                                short* __restrict__ owO) {
  const int bid = blockIdx.x;
  const float* in;
  short* out;
  int ib;
  if (bid < 8192)        { in = iQ; out = oQ; ib = bid; }
  else if (bid < 16384)  { in = iK; out = oK; ib = bid - 8192; }
  else if (bid < 24576)  { in = iV; out = oV; ib = bid - 16384; }
  else {
    const int wb = bid - 24576;       // 0..4095, 1024 blocks per weight
    const int sel = wb >> 10;
    in  = sel == 0 ? wQ : (sel == 1 ? wK : (sel == 2 ? wV : wO));
    out = sel == 0 ? owQ : (sel == 1 ? owK : (sel == 2 ? owV : owO));
    ib = wb & 1023;
  }
  const int i = ib * 256 + threadIdx.x;
  float4 v = reinterpret_cast<const float4*>(in)[i];
  uint32_t lo = pk2bf(v.x, v.y), hi = pk2bf(v.z, v.w);
  uint64_t pk = (uint64_t)lo | ((uint64_t)hi << 32);
  reinterpret_cast<uint64_t*>(out)[i] = pk;
}

// ---------------- GEMM core: 128x128 tile, BK=64, 4 waves ----------------
template <int MODE>
static __device__ __forceinline__ void gemm_body(const short* __restrict__ A,
                                                 const short* __restrict__ Bt,
                                                 void* __restrict__ out,
                                                 int bm, int bn) {
  __shared__ __align__(16) short lA[128 * 64];
  __shared__ __align__(16) short lB[128 * 64];
  const int tid = threadIdx.x;
  const int lane = tid & 63, w = tid >> 6;
  const int wr = w >> 1, wc = w & 1;
  const int r = lane & 15, g = lane >> 4;

  const int lrow8 = lane >> 3;           // 0..7
  const int lsl   = lane & 7;            // raw slot

  f32x4 acc[4][4] = {};
  const short* Ab = A + (size_t)bm * DMc;
  const short* Bb = Bt + (size_t)bn * DMc;

  for (int k0 = 0; k0 < DMc; k0 += 64) {
    __syncthreads();
    #pragma unroll
    for (int rnd = 0; rnd < 4; rnd++) {
      const int row = rnd * 32 + w * 8 + lrow8;
      const int slot = lsl ^ (row & 7);
      gload16(Ab + (size_t)row * DMc + k0 + slot * 8, lA + (rnd * 32 + w * 8) * 64);
      gload16(Bb + (size_t)row * DMc + k0 + slot * 8, lB + (rnd * 32 + w * 8) * 64);
    }
    __syncthreads();

    #pragma unroll
    for (int kk = 0; kk < 2; kk++) {
      bf16x8 af[4], bfr[4];
      #pragma unroll
      for (int i = 0; i < 4; i++) {
        const int arow = wr * 64 + i * 16 + r;
        af[i] = *reinterpret_cast<const bf16x8*>(
            lA + arow * 64 + (((kk * 4 + g) ^ (arow & 7)) << 3));
        const int brow = wc * 64 + i * 16 + r;
        bfr[i] = *reinterpret_cast<const bf16x8*>(
            lB + brow * 64 + (((kk * 4 + g) ^ (brow & 7)) << 3));
      }
      #pragma unroll
      for (int i = 0; i < 4; i++)
        #pragma unroll
        for (int n = 0; n < 4; n++) acc[i][n] = mfma16(af[i], bfr[n], acc[i][n]);
    }
  }

  #pragma unroll
  for (int i = 0; i < 4; i++) {
    #pragma unroll
    for (int n = 0; n < 4; n++) {
      const int col = bn + wc * 64 + n * 16 + r;
      #pragma unroll
      for (int j = 0; j < 4; j++) {
        const int m = bm + wr * 64 + i * 16 + g * 4 + j;
        if (MODE == 2) {
          reinterpret_cast<float*>(out)[(size_t)m * DMc + col] = acc[i][n][j];
        } else {
          const int b = m >> 11, s = m & (Sc - 1);
          const int h = col >> 6, d = col & (DHc - 1);
          size_t idx = (MODE == 1)
              ? ((size_t)(b * Hc + h) * DHc + d) * Sc + s     // Vt [BH][64][S]
              : ((size_t)(b * Hc + h) * Sc + s) * DHc + d;    // Q/K [BH][S][64]
          reinterpret_cast<short*>(out)[idx] = f2bf(acc[i][n][j]);
        }
      }
    }
  }
}

// ---- merged: Q/K/V projections (blocks 0..1535) + mask bit-pack (1536..3583) ----
__global__ __launch_bounds__(256) void k_gemmQKV_pack(
    const short* __restrict__ XQ, const short* __restrict__ XK,
    const short* __restrict__ XV, const short* __restrict__ WQ,
    const short* __restrict__ WK, const short* __restrict__ WV,
    short* __restrict__ Q, short* __restrict__ K, short* __restrict__ V,
    const int* __restrict__ msk, uint32_t* __restrict__ bits) {
  const int bid = blockIdx.x;
  if (bid < 1536) {
    const int rem = bid & 511;
    const int bm = (rem & 63) * 128, bn = (rem >> 6) * 128;
    const int z = bid >> 9;
    if (z == 0)      gemm_body<0>(XQ, WQ, (void*)Q, bm, bn);
    else if (z == 1) gemm_body<0>(XK, WK, (void*)K, bm, bn);
    else             gemm_body<1>(XV, WV, (void*)V, bm, bn);
  } else {
    // pack: one uint32 word (32 mask ints) per thread
    const size_t wi = (size_t)(bid - 1536) * 256 + threadIdx.x;  // word index
    const uint4* mp = reinterpret_cast<const uint4*>(msk + wi * 32);
    uint32_t word = 0;
    #pragma unroll
    for (int q = 0; q < 8; q++) {
      const uint4 mv = mp[q];
      word |= (mv.x != 0 ? 1u : 0u) << (q * 4 + 0);
      word |= (mv.y != 0 ? 1u : 0u) << (q * 4 + 1);
      word |= (mv.z != 0 ? 1u : 0u) << (q * 4 + 2);
      word |= (mv.w != 0 ? 1u : 0u) << (q * 4 + 3);
    }
    bits[wi] = word;
  }
}

// ---------------- fused flash ctx + attn writer ----------
// r10 structure, but SINGLE-buffered K/V staging: LDS 48->32 KB so 4 blocks/CU
// (launch_bounds(512,8); VGPR<=64) instead of 3. Bet: cross-block TLP (m114)
// hides the per-kt stage drain better than intra-block dbuf did, and the extra
// co-resident block improves phase-1/phase-2 (MFMA vs store-stream) overlap.
__global__ __launch_bounds__(512, 8) void k_flash2(const short* __restrict__ Qb,
                                                   const short* __restrict__ Kb,
                                                   const short* __restrict__ Vt,
                                                   const uint32_t* __restrict__ pbits,
                                                   short* __restrict__ ctx,
                                                   float* __restrict__ attn) {
  __shared__ __align__(16) short kbuf[4096];     // [64 k-rows][64 d], 8 KB
  __shared__ __align__(16) short vbuf[4096];     // [64 d-rows][64 k], 8 KB
  __shared__ __align__(16) short pbuf[8][1024];  // per-wave [16 q][64 k] bf16, 16 KB

  // XCD-aware decode: lin -> (xcd = lin&7, slot = lin>>3); bh = xcd*8 + slot/16
  const int lin = blockIdx.x;
  const int bh = (lin & 7) * 8 + (lin >> 7);
  const int qbase = ((lin >> 3) & 15) * 128;
  const int b = bh >> 4, h = bh & 15;
  const int tid = threadIdx.x;
  const int lane = tid & 63, w = tid >> 6;
  const int r = lane & 15, g = lane >> 4;
  const int rx = r & 7;

  // staging thread->element map: row = tid>>3, slot = (tid&7) ^ (row&7)
  const int srow = tid >> 3;
  const int sslot = (tid & 7) ^ (srow & 7);
  const short* ksrc = Kb + ((size_t)bh * Sc + srow) * DHc + sslot * 8;
  const short* vsrc = Vt + ((size_t)bh * DHc + srow) * Sc + sslot * 8;
  short* const kdst = &kbuf[w * 512];
  short* const vdst = &vbuf[w * 512];

  // Q fragment for my 16 rows (q = qbase + w*16 + r)
  const short* qrow = Qb + ((size_t)bh * Sc + qbase + w * 16 + r) * DHc;
  const bf16x8 qf0 = *reinterpret_cast<const bf16x8*>(qrow + g * 8);
  const bf16x8 qf1 = *reinterpret_cast<const bf16x8*>(qrow + g * 8 + 32);

  const uint32_t* mrow = pbits + ((size_t)b * Sc + qbase + w * 16 + r) * (Sc / 32);

  constexpr float SCL = 0.18033688f;  // log2(e)/8
  f32x4 pacc[4] = {};
  float rs = 0.f;

  // ---- phase 1: flash sweep (single-buffered staging) ----
  for (int kt = 0; kt < 32; kt++) {
    __syncthreads();  // all waves done reading buf from previous kt
    gload16(ksrc + (size_t)kt * 64 * DHc, kdst);
    gload16(vsrc + kt * 64,               vdst);
    __syncthreads();  // compiler drains vmcnt before barrier -> staged data ready

    // QK^T: 4 t-tiles of 16 k, d=64 as 2 MFMAs
    f32x4 sc4[4];
    #pragma unroll
    for (int tt = 0; tt < 4; tt++) {
      const int krow = (tt * 16 + r) * 64;
      bf16x8 kf0 = *reinterpret_cast<const bf16x8*>(kbuf + krow + ((g ^ rx) << 3));
      bf16x8 kf1 = *reinterpret_cast<const bf16x8*>(kbuf + krow + (((g + 4) ^ rx) << 3));
      f32x4 a = {};
      a = mfma16(kf0, qf0, a);
      a = mfma16(kf1, qf1, a);
      sc4[tt] = a;  // S[q=qbase+w*16+r][k=kt*64+tt*16+g*4+j]
    }

    // mask + exp (no max-sub) + row-sum + pack P -> pbuf (v_cvt_pk_bf16_f32)
    const uint2 mu = *reinterpret_cast<const uint2*>(mrow + kt * 2);
    #pragma unroll
    for (int tt = 0; tt < 4; tt++) {
      const uint32_t mword = (tt < 2) ? mu.x : mu.y;
      const int bsh = (tt & 1) * 16 + g * 4;
      f32x4 e;
      #pragma unroll
      for (int j = 0; j < 4; j++) {
        float v = __builtin_exp2f(sc4[tt][j] * SCL);
        if ((mword >> (bsh + j)) & 1u) v = 0.f;
        e[j] = v;
        rs += v;
      }
      uint32_t lo = pk2bf(e[0], e[1]);
      uint32_t hi = pk2bf(e[2], e[3]);
      uint64_t pk = (uint64_t)lo | ((uint64_t)hi << 32);
      *reinterpret_cast<uint64_t*>(
          &pbuf[w][r * 64 + (((tt * 2 + (g >> 1)) ^ rx) << 3) + ((g & 1) << 2)]) = pk;
    }

    // PV: same-wave pbuf read (lgkm-ordered), V from LDS
    #pragma unroll
    for (int kt2 = 0; kt2 < 2; kt2++) {
      const int sl = ((kt2 * 4 + g) ^ rx) << 3;
      const bf16x8 paf = *reinterpret_cast<const bf16x8*>(&pbuf[w][r * 64 + sl]);
      #pragma unroll
      for (int n = 0; n < 4; n++) {
        const bf16x8 vf = *reinterpret_cast<const bf16x8*>(vbuf + (n * 16 + r) * 64 + sl);
        pacc[n] = mfma16(paf, vf, pacc[n]);
      }
    }
  }

  // row sums: combine the 4 g-groups
  rs += __shfl_xor(rs, 16);
  rs += __shfl_xor(rs, 32);
  const float rinv = 1.0f / rs;   // rinv for row q = qbase + w*16 + r

  float riv[4];
  #pragma unroll
  for (int j = 0; j < 4; j++) riv[j] = 1.0f / __shfl(rs, g * 4 + j);

  // ctx write: pacc[n][j] = ctx[q=qbase+w*16+g*4+j][d=n*16+r]
  short* cbase = ctx + ((size_t)b * Sc + qbase + w * 16) * DMc + h * DHc;
  #pragma unroll
  for (int n = 0; n < 4; n++)
    #pragma unroll
    for (int j = 0; j < 4; j++)
      cbase[(size_t)(g * 4 + j) * DMc + n * 16 + r] = f2bf(pacc[n][j] * riv[j]);

  // ---- phase 2: normalized attn stream (per-wave, no barriers) ----
  const short* kbase = Kb + (size_t)bh * Sc * DHc;
  float* out = attn + ((size_t)bh * Sc + qbase + w * 16 + r) * Sc;
  #pragma unroll 2
  for (int kt = 0; kt < 32; kt++) {
    const uint2 mu = *reinterpret_cast<const uint2*>(mrow + kt * 2);
    #pragma unroll
    for (int tt = 0; tt < 4; tt++) {
      const short* krow = kbase + (size_t)(kt * 64 + tt * 16 + r) * DHc;
      bf16x8 kf0 = *reinterpret_cast<const bf16x8*>(krow + g * 8);
      bf16x8 kf1 = *reinterpret_cast<const bf16x8*>(krow + g * 8 + 32);
      f32x4 a = {};
      a = mfma16(kf0, qf0, a);
      a = mfma16(kf1, qf1, a);
      const uint32_t mword = (tt < 2) ? mu.x : mu.y;
      const int bsh = (tt & 1) * 16 + g * 4;
      f32x4 o;
      #pragma unroll
      for (int j = 0; j < 4; j++) {
        float v = __builtin_exp2f(a[j] * SCL) * rinv;
        if ((mword >> (bsh + j)) & 1u) v = 0.f;
        o[j] = v;
      }
      __builtin_nontemporal_store(
          o, reinterpret_cast<f32x4*>(out + kt * 64 + tt * 16 + g * 4));
    }
  }
}

// output projection (f32 out)
__global__ __launch_bounds__(256) void k_gemmO(const short* __restrict__ A,
                                               const short* __restrict__ Bt,
                                               float* __restrict__ out) {
  gemm_body<2>(A, Bt, (void*)out, blockIdx.x * 128, blockIdx.y * 128);
}

// ---------------- residual + LayerNorm ----------------
__global__ __launch_bounds__(256) void k_ln(const float* __restrict__ y,
                                            const float* __restrict__ resid,
                                            float* __restrict__ out) {
  const int m = blockIdx.x, t = threadIdx.x;
  const float4 a = reinterpret_cast<const float4*>(y + (size_t)m * DMc)[t];
  const float4 b = reinterpret_cast<const float4*>(resid + (size_t)m * DMc)[t];
  float x0 = a.x + b.x, x1 = a.y + b.y, x2 = a.z + b.z, x3 = a.w + b.w;

  float s = x0 + x1 + x2 + x3;
  #pragma unroll
  for (int m2 = 1; m2 < 64; m2 <<= 1) s += __shfl_xor(s, m2);
  __shared__ float red[4];
  __shared__ float red2[4];
  const int w = t >> 6, lane = t & 63;
  if (lane == 0) red[w] = s;
  __syncthreads();
  const float mean = (red[0] + red[1] + red[2] + red[3]) * (1.0f / DMc);

  x0 -= mean; x1 -= mean; x2 -= mean; x3 -= mean;
  float s2 = x0 * x0 + x1 * x1 + x2 * x2 + x3 * x3;
  #pragma unroll
  for (int m2 = 1; m2 < 64; m2 <<= 1) s2 += __shfl_xor(s2, m2);
  if (lane == 0) red2[w] = s2;
  __syncthreads();
  const float var = (red2[0] + red2[1] + red2[2] + red2[3]) * (1.0f / DMc);
  const float rstd = rsqrtf(var + 1e-5f);

  float4 o;
  o.x = x0 * rstd; o.y = x1 * rstd; o.z = x2 * rstd; o.w = x3 * rstd;
  reinterpret_cast<float4*>(out + (size_t)m * DMc)[t] = o;
}

extern "C" void kernel_launch(void* const* d_in, const int* in_sizes, int n_in,
                              void* d_out, int out_size, void* d_ws, size_t ws_size,
                              hipStream_t stream) {
  const float* inQ = (const float*)d_in[0];
  const float* inK = (const float*)d_in[1];
  const float* inV = (const float*)d_in[2];
  const int*   msk = (const int*)d_in[3];
  const float* WQ  = (const float*)d_in[4];
  const float* WK  = (const float*)d_in[5];
  const float* WV  = (const float*)d_in[6];
  const float* Wfc = (const float*)d_in[7];

  float* out_ln   = (float*)d_out;                       // [B,S,1024] f32
  float* out_attn = out_ln + (size_t)Bc * Sc * DMc;      // [B,H,S,S] f32

  const size_t NX = (size_t)Bc * Sc * DMc;  // 8,388,608
  const size_t NW = (size_t)DMc * DMc;      // 1,048,576
  short* ws = (short*)d_ws;
  short* XbQ = ws;                 // bf16 inputs
  short* XbK = XbQ + NX;
  short* XbV = XbK + NX;
  short* WQb = XbV + NX;           // bf16 weights
  short* WKb = WQb + NW;
  short* WVb = WKb + NW;
  short* Wfb = WVb + NW;
  short* Qb  = Wfb + NW;           // [BH][S][64]
  short* Kb  = Qb + NX;            // [BH][S][64]
  short* Vt  = Kb + NX;            // [BH][64][S]
  uint32_t* pbits = (uint32_t*)(Vt + NX);  // [B][S][64 words], 2 MB
  short* ctx = XbV;                // aliases XbV (dead after V-proj)
  float* y   = (float*)XbQ;        // aliases XbQ+XbK (dead after Q/K-proj)

  // 1) all conversions in one launch
  k_cvtall<<<dim3(28672), 256, 0, stream>>>(inQ, inK, inV, WQ, WK, WV, Wfc,
                                            XbQ, XbK, XbV, WQb, WKb, WVb, Wfb);

  // 2) Q/K/V projections + mask pack merged
  k_gemmQKV_pack<<<dim3(1536 + 2048), 256, 0, stream>>>(
      XbQ, XbK, XbV, WQb, WKb, WVb, Qb, Kb, Vt, msk, pbits);

  // 3) fused flash ctx + attn stream (XCD-swizzled linear grid)
  k_flash2<<<dim3(1024), 512, 0, stream>>>(Qb, Kb, Vt, pbits, ctx, out_attn);

  // 4) output projection -> y (f32)
  k_gemmO<<<dim3(Bc * Sc / 128, DMc / 128), 256, 0, stream>>>(ctx, Wfb, y);

  // 5) residual + LayerNorm -> ln (output 0)
  k_ln<<<dim3(Bc * Sc), 256, 0, stream>>>(y, inQ, out_ln);
}

// Round 16
// 546.447 us; speedup vs baseline: 1.0902x; 1.0902x over previous
//
#include <hip/hip_runtime.h>
#include <hip/hip_bf16.h>
#include <cstdint>
#include <cstddef>

// Problem constants
constexpr int Bc  = 4;
constexpr int Sc  = 2048;
constexpr int DMc = 1024;   // d_model
constexpr int Hc  = 16;     // heads
constexpr int DHc = 64;     // head dim
constexpr int BHc = Bc * Hc;

typedef float f32x4  __attribute__((ext_vector_type(4)));
typedef short bf16x8 __attribute__((ext_vector_type(8)));

// f32 -> bf16 (RNE), scalar fallback
static __device__ __forceinline__ short f2bf(float x) {
  uint32_t u = __builtin_bit_cast(uint32_t, x);
  u += 0x7fffu + ((u >> 16) & 1u);
  return (short)(u >> 16);
}

// 2x f32 -> packed 2x bf16 (RNE) via v_cvt_pk_bf16_f32 (1 VALU op)
static __device__ __forceinline__ uint32_t pk2bf(float a, float b) {
  __hip_bfloat162 h = __float22bfloat162_rn(float2{a, b});
  uint32_t r;
  __builtin_memcpy(&r, &h, 4);
  return r;
}

static __device__ __forceinline__ f32x4 mfma16(bf16x8 a, bf16x8 b, f32x4 c) {
  return __builtin_amdgcn_mfma_f32_16x16x32_bf16(a, b, c, 0, 0, 0);
}

// async global->LDS, 16B per lane. LDS dest is wave-uniform base + lane*16.
static __device__ __forceinline__ void gload16(const short* g, short* l) {
  __builtin_amdgcn_global_load_lds(
      (const __attribute__((address_space(1))) void*)g,
      (__attribute__((address_space(3))) void*)l, 16, 0, 0);
}

// ---------------- all f32->bf16 conversions in ONE launch ----------------
__global__ __launch_bounds__(256) void k_cvtall(const float* __restrict__ iQ,
                                                const float* __restrict__ iK,
                                                const float* __restrict__ iV,
                                                const float* __restrict__ wQ,
                                                const float* __restrict__ wK,
                                                const float* __restrict__ wV,
                                                const float* __restrict__ wO,
                                                short* __restrict__ oQ,
                                                short* __restrict__ oK,
                                                short* __restrict__ oV,
                                                short* __restrict__ owQ,
                                                short* __restrict__ owK,
                                                short* __restrict__ owV,
                                                short* __restrict__ owO) {
  const int bid = blockIdx.x;
  const float* in;
  short* out;
  int ib;
  if (bid < 8192)        { in = iQ; out = oQ; ib = bid; }
  else if (bid < 16384)  { in = iK; out = oK; ib = bid - 8192; }
  else if (bid < 24576)  { in = iV; out = oV; ib = bid - 16384; }
  else {
    const int wb = bid - 24576;       // 0..4095, 1024 blocks per weight
    const int sel = wb >> 10;
    in  = sel == 0 ? wQ : (sel == 1 ? wK : (sel == 2 ? wV : wO));
    out = sel == 0 ? owQ : (sel == 1 ? owK : (sel == 2 ? owV : owO));
    ib = wb & 1023;
  }
  const int i = ib * 256 + threadIdx.x;
  float4 v = reinterpret_cast<const float4*>(in)[i];
  uint32_t lo = pk2bf(v.x, v.y), hi = pk2bf(v.z, v.w);
  uint64_t pk = (uint64_t)lo | ((uint64_t)hi << 32);
  reinterpret_cast<uint64_t*>(out)[i] = pk;
}

// ---------------- GEMM core: 128x128 tile, BK=64, 4 waves ----------------
template <int MODE>
static __device__ __forceinline__ void gemm_body(const short* __restrict__ A,
                                                 const short* __restrict__ Bt,
                                                 void* __restrict__ out,
                                                 int bm, int bn) {
  __shared__ __align__(16) short lA[128 * 64];
  __shared__ __align__(16) short lB[128 * 64];
  const int tid = threadIdx.x;
  const int lane = tid & 63, w = tid >> 6;
  const int wr = w >> 1, wc = w & 1;
  const int r = lane & 15, g = lane >> 4;

  const int lrow8 = lane >> 3;           // 0..7
  const int lsl   = lane & 7;            // raw slot

  f32x4 acc[4][4] = {};
  const short* Ab = A + (size_t)bm * DMc;
  const short* Bb = Bt + (size_t)bn * DMc;

  for (int k0 = 0; k0 < DMc; k0 += 64) {
    __syncthreads();
    #pragma unroll
    for (int rnd = 0; rnd < 4; rnd++) {
      const int row = rnd * 32 + w * 8 + lrow8;
      const int slot = lsl ^ (row & 7);
      gload16(Ab + (size_t)row * DMc + k0 + slot * 8, lA + (rnd * 32 + w * 8) * 64);
      gload16(Bb + (size_t)row * DMc + k0 + slot * 8, lB + (rnd * 32 + w * 8) * 64);
    }
    __syncthreads();

    #pragma unroll
    for (int kk = 0; kk < 2; kk++) {
      bf16x8 af[4], bfr[4];
      #pragma unroll
      for (int i = 0; i < 4; i++) {
        const int arow = wr * 64 + i * 16 + r;
        af[i] = *reinterpret_cast<const bf16x8*>(
            lA + arow * 64 + (((kk * 4 + g) ^ (arow & 7)) << 3));
        const int brow = wc * 64 + i * 16 + r;
        bfr[i] = *reinterpret_cast<const bf16x8*>(
            lB + brow * 64 + (((kk * 4 + g) ^ (brow & 7)) << 3));
      }
      #pragma unroll
      for (int i = 0; i < 4; i++)
        #pragma unroll
        for (int n = 0; n < 4; n++) acc[i][n] = mfma16(af[i], bfr[n], acc[i][n]);
    }
  }

  #pragma unroll
  for (int i = 0; i < 4; i++) {
    #pragma unroll
    for (int n = 0; n < 4; n++) {
      const int col = bn + wc * 64 + n * 16 + r;
      #pragma unroll
      for (int j = 0; j < 4; j++) {
        const int m = bm + wr * 64 + i * 16 + g * 4 + j;
        if (MODE == 2) {
          reinterpret_cast<float*>(out)[(size_t)m * DMc + col] = acc[i][n][j];
        } else {
          const int b = m >> 11, s = m & (Sc - 1);
          const int h = col >> 6, d = col & (DHc - 1);
          size_t idx = (MODE == 1)
              ? ((size_t)(b * Hc + h) * DHc + d) * Sc + s     // Vt [BH][64][S]
              : ((size_t)(b * Hc + h) * Sc + s) * DHc + d;    // Q/K [BH][S][64]
          reinterpret_cast<short*>(out)[idx] = f2bf(acc[i][n][j]);
        }
      }
    }
  }
}

// ---- merged: Q/K/V projections (blocks 0..1535) + mask bit-pack (1536..3583) ----
__global__ __launch_bounds__(256) void k_gemmQKV_pack(
    const short* __restrict__ XQ, const short* __restrict__ XK,
    const short* __restrict__ XV, const short* __restrict__ WQ,
    const short* __restrict__ WK, const short* __restrict__ WV,
    short* __restrict__ Q, short* __restrict__ K, short* __restrict__ V,
    const int* __restrict__ msk, uint32_t* __restrict__ bits) {
  const int bid = blockIdx.x;
  if (bid < 1536) {
    const int rem = bid & 511;
    const int bm = (rem & 63) * 128, bn = (rem >> 6) * 128;
    const int z = bid >> 9;
    if (z == 0)      gemm_body<0>(XQ, WQ, (void*)Q, bm, bn);
    else if (z == 1) gemm_body<0>(XK, WK, (void*)K, bm, bn);
    else             gemm_body<1>(XV, WV, (void*)V, bm, bn);
  } else {
    // pack: one uint32 word (32 mask ints) per thread
    const size_t wi = (size_t)(bid - 1536) * 256 + threadIdx.x;  // word index
    const uint4* mp = reinterpret_cast<const uint4*>(msk + wi * 32);
    uint32_t word = 0;
    #pragma unroll
    for (int q = 0; q < 8; q++) {
      const uint4 mv = mp[q];
      word |= (mv.x != 0 ? 1u : 0u) << (q * 4 + 0);
      word |= (mv.y != 0 ? 1u : 0u) << (q * 4 + 1);
      word |= (mv.z != 0 ? 1u : 0u) << (q * 4 + 2);
      word |= (mv.w != 0 ? 1u : 0u) << (q * 4 + 3);
    }
    bits[wi] = word;
  }
}

// ---------------- fused flash ctx + attn writer (round-10 structure) ----------
// grid 1024 linear blocks -> XCD-swizzled (bh, qbase): all 16 q-blocks of one
// head land on one XCD (shared 512KB K/V working set stays in that L2).
// Phase 1: staged K/V sweep (global_load_lds double-buffer), P in per-wave LDS
//   (packed via v_cvt_pk_bf16_f32), ctx accumulate + row sums.
// Phase 2: per-wave barrier-free normalized attn stream.
__global__ __launch_bounds__(512, 4) void k_flash2(const short* __restrict__ Qb,
                                                   const short* __restrict__ Kb,
                                                   const short* __restrict__ Vt,
                                                   const uint32_t* __restrict__ pbits,
                                                   short* __restrict__ ctx,
                                                   float* __restrict__ attn) {
  __shared__ __align__(16) short kbuf[2][4096];  // [64 k-rows][64 d] x dbuf, 16 KB
  __shared__ __align__(16) short vbuf[2][4096];  // [64 d-rows][64 k] x dbuf, 16 KB
  __shared__ __align__(16) short pbuf[8][1024];  // per-wave [16 q][64 k] bf16, 16 KB

  // XCD-aware decode: lin -> (xcd = lin&7, slot = lin>>3); bh = xcd*8 + slot/16
  const int lin = blockIdx.x;
  const int bh = (lin & 7) * 8 + (lin >> 7);
  const int qbase = ((lin >> 3) & 15) * 128;
  const int b = bh >> 4, h = bh & 15;
  const int tid = threadIdx.x;
  const int lane = tid & 63, w = tid >> 6;
  const int r = lane & 15, g = lane >> 4;
  const int rx = r & 7;

  // staging thread->element map: row = tid>>3, slot = (tid&7) ^ (row&7)
  const int srow = tid >> 3;
  const int sslot = (tid & 7) ^ (srow & 7);
  const short* ksrc = Kb + ((size_t)bh * Sc + srow) * DHc + sslot * 8;
  const short* vsrc = Vt + ((size_t)bh * DHc + srow) * Sc + sslot * 8;
  short* const kdst0 = &kbuf[0][w * 512];
  short* const kdst1 = &kbuf[1][w * 512];
  short* const vdst0 = &vbuf[0][w * 512];
  short* const vdst1 = &vbuf[1][w * 512];

  // Q fragment for my 16 rows (q = qbase + w*16 + r)
  const short* qrow = Qb + ((size_t)bh * Sc + qbase + w * 16 + r) * DHc;
  const bf16x8 qf0 = *reinterpret_cast<const bf16x8*>(qrow + g * 8);
  const bf16x8 qf1 = *reinterpret_cast<const bf16x8*>(qrow + g * 8 + 32);

  const uint32_t* mrow = pbits + ((size_t)b * Sc + qbase + w * 16 + r) * (Sc / 32);

  constexpr float SCL = 0.18033688f;  // log2(e)/8
  f32x4 pacc[4] = {};
  float rs = 0.f;

  // ---- phase 1: flash sweep ----
  gload16(ksrc, kdst0);
  gload16(vsrc, vdst0);
  __syncthreads();  // compiler drains vmcnt before barrier

  int cur = 0;
  for (int kt = 0; kt < 32; kt++) {
    if (kt + 1 < 32) {
      gload16(ksrc + (size_t)(kt + 1) * 64 * DHc, cur ? kdst0 : kdst1);
      gload16(vsrc + (kt + 1) * 64,               cur ? vdst0 : vdst1);
    }
    const short* kb = kbuf[cur];
    const short* vb = vbuf[cur];

    // QK^T: 4 t-tiles of 16 k, d=64 as 2 MFMAs
    f32x4 sc4[4];
    #pragma unroll
    for (int tt = 0; tt < 4; tt++) {
      const int krow = (tt * 16 + r) * 64;
      bf16x8 kf0 = *reinterpret_cast<const bf16x8*>(kb + krow + ((g ^ rx) << 3));
      bf16x8 kf1 = *reinterpret_cast<const bf16x8*>(kb + krow + (((g + 4) ^ rx) << 3));
      f32x4 a = {};
      a = mfma16(kf0, qf0, a);
      a = mfma16(kf1, qf1, a);
      sc4[tt] = a;  // S[q=qbase+w*16+r][k=kt*64+tt*16+g*4+j]
    }

    // mask + exp (no max-sub) + row-sum + pack P -> pbuf (v_cvt_pk_bf16_f32)
    const uint2 mu = *reinterpret_cast<const uint2*>(mrow + kt * 2);
    #pragma unroll
    for (int tt = 0; tt < 4; tt++) {
      const uint32_t mword = (tt < 2) ? mu.x : mu.y;
      const int bsh = (tt & 1) * 16 + g * 4;
      f32x4 e;
      #pragma unroll
      for (int j = 0; j < 4; j++) {
        float v = __builtin_exp2f(sc4[tt][j] * SCL);
        if ((mword >> (bsh + j)) & 1u) v = 0.f;
        e[j] = v;
        rs += v;
      }
      uint32_t lo = pk2bf(e[0], e[1]);
      uint32_t hi = pk2bf(e[2], e[3]);
      uint64_t pk = (uint64_t)lo | ((uint64_t)hi << 32);
      *reinterpret_cast<uint64_t*>(
          &pbuf[w][r * 64 + (((tt * 2 + (g >> 1)) ^ rx) << 3) + ((g & 1) << 2)]) = pk;
    }

    // PV: same-wave pbuf read (lgkm-ordered), V from LDS
    #pragma unroll
    for (int kt2 = 0; kt2 < 2; kt2++) {
      const int sl = ((kt2 * 4 + g) ^ rx) << 3;
      const bf16x8 paf = *reinterpret_cast<const bf16x8*>(&pbuf[w][r * 64 + sl]);
      #pragma unroll
      for (int n = 0; n < 4; n++) {
        const bf16x8 vf = *reinterpret_cast<const bf16x8*>(vb + (n * 16 + r) * 64 + sl);
        pacc[n] = mfma16(paf, vf, pacc[n]);
      }
    }

    __syncthreads();  // staged kt+1 resident; all waves done with buf[cur]
    cur ^= 1;
  }

  // row sums: combine the 4 g-groups
  rs += __shfl_xor(rs, 16);
  rs += __shfl_xor(rs, 32);
  const float rinv = 1.0f / rs;   // rinv for row q = qbase + w*16 + r

  float riv[4];
  #pragma unroll
  for (int j = 0; j < 4; j++) riv[j] = 1.0f / __shfl(rs, g * 4 + j);

  // ctx write: pacc[n][j] = ctx[q=qbase+w*16+g*4+j][d=n*16+r]
  short* cbase = ctx + ((size_t)b * Sc + qbase + w * 16) * DMc + h * DHc;
  #pragma unroll
  for (int n = 0; n < 4; n++)
    #pragma unroll
    for (int j = 0; j < 4; j++)
      cbase[(size_t)(g * 4 + j) * DMc + n * 16 + r] = f2bf(pacc[n][j] * riv[j]);

  // ---- phase 2: normalized attn stream (per-wave, no barriers) ----
  const short* kbase = Kb + (size_t)bh * Sc * DHc;
  float* out = attn + ((size_t)bh * Sc + qbase + w * 16 + r) * Sc;
  #pragma unroll 2
  for (int kt = 0; kt < 32; kt++) {
    const uint2 mu = *reinterpret_cast<const uint2*>(mrow + kt * 2);
    #pragma unroll
    for (int tt = 0; tt < 4; tt++) {
      const short* krow = kbase + (size_t)(kt * 64 + tt * 16 + r) * DHc;
      bf16x8 kf0 = *reinterpret_cast<const bf16x8*>(krow + g * 8);
      bf16x8 kf1 = *reinterpret_cast<const bf16x8*>(krow + g * 8 + 32);
      f32x4 a = {};
      a = mfma16(kf0, qf0, a);
      a = mfma16(kf1, qf1, a);
      const uint32_t mword = (tt < 2) ? mu.x : mu.y;
      const int bsh = (tt & 1) * 16 + g * 4;
      f32x4 o;
      #pragma unroll
      for (int j = 0; j < 4; j++) {
        float v = __builtin_exp2f(a[j] * SCL) * rinv;
        if ((mword >> (bsh + j)) & 1u) v = 0.f;
        o[j] = v;
      }
      __builtin_nontemporal_store(
          o, reinterpret_cast<f32x4*>(out + kt * 64 + tt * 16 + g * 4));
    }
  }
}

// output projection (f32 out)
__global__ __launch_bounds__(256) void k_gemmO(const short* __restrict__ A,
                                               const short* __restrict__ Bt,
                                               float* __restrict__ out) {
  gemm_body<2>(A, Bt, (void*)out, blockIdx.x * 128, blockIdx.y * 128);
}

// ---------------- residual + LayerNorm ----------------
__global__ __launch_bounds__(256) void k_ln(const float* __restrict__ y,
                                            const float* __restrict__ resid,
                                            float* __restrict__ out) {
  const int m = blockIdx.x, t = threadIdx.x;
  const float4 a = reinterpret_cast<const float4*>(y + (size_t)m * DMc)[t];
  const float4 b = reinterpret_cast<const float4*>(resid + (size_t)m * DMc)[t];
  float x0 = a.x + b.x, x1 = a.y + b.y, x2 = a.z + b.z, x3 = a.w + b.w;

  float s = x0 + x1 + x2 + x3;
  #pragma unroll
  for (int m2 = 1; m2 < 64; m2 <<= 1) s += __shfl_xor(s, m2);
  __shared__ float red[4];
  __shared__ float red2[4];
  const int w = t >> 6, lane = t & 63;
  if (lane == 0) red[w] = s;
  __syncthreads();
  const float mean = (red[0] + red[1] + red[2] + red[3]) * (1.0f / DMc);

  x0 -= mean; x1 -= mean; x2 -= mean; x3 -= mean;
  float s2 = x0 * x0 + x1 * x1 + x2 * x2 + x3 * x3;
  #pragma unroll
  for (int m2 = 1; m2 < 64; m2 <<= 1) s2 += __shfl_xor(s2, m2);
  if (lane == 0) red2[w] = s2;
  __syncthreads();
  const float var = (red2[0] + red2[1] + red2[2] + red2[3]) * (1.0f / DMc);
  const float rstd = rsqrtf(var + 1e-5f);

  float4 o;
  o.x = x0 * rstd; o.y = x1 * rstd; o.z = x2 * rstd; o.w = x3 * rstd;
  reinterpret_cast<float4*>(out + (size_t)m * DMc)[t] = o;
}

extern "C" void kernel_launch(void* const* d_in, const int* in_sizes, int n_in,
                              void* d_out, int out_size, void* d_ws, size_t ws_size,
                              hipStream_t stream) {
  const float* inQ = (const float*)d_in[0];
  const float* inK = (const float*)d_in[1];
  const float* inV = (const float*)d_in[2];
  const int*   msk = (const int*)d_in[3];
  const float* WQ  = (const float*)d_in[4];
  const float* WK  = (const float*)d_in[5];
  const float* WV  = (const float*)d_in[6];
  const float* Wfc = (const float*)d_in[7];

  float* out_ln   = (float*)d_out;                       // [B,S,1024] f32
  float* out_attn = out_ln + (size_t)Bc * Sc * DMc;      // [B,H,S,S] f32

  const size_t NX = (size_t)Bc * Sc * DMc;  // 8,388,608
  const size_t NW = (size_t)DMc * DMc;      // 1,048,576
  short* ws = (short*)d_ws;
  short* XbQ = ws;                 // bf16 inputs
  short* XbK = XbQ + NX;
  short* XbV = XbK + NX;
  short* WQb = XbV + NX;           // bf16 weights
  short* WKb = WQb + NW;
  short* WVb = WKb + NW;
  short* Wfb = WVb + NW;
  short* Qb  = Wfb + NW;           // [BH][S][64]
  short* Kb  = Qb + NX;            // [BH][S][64]
  short* Vt  = Kb + NX;            // [BH][64][S]
  uint32_t* pbits = (uint32_t*)(Vt + NX);  // [B][S][64 words], 2 MB
  short* ctx = XbV;                // aliases XbV (dead after V-proj)
  float* y   = (float*)XbQ;        // aliases XbQ+XbK (dead after Q/K-proj)

  // 1) all conversions in one launch
  k_cvtall<<<dim3(28672), 256, 0, stream>>>(inQ, inK, inV, WQ, WK, WV, Wfc,
                                            XbQ, XbK, XbV, WQb, WKb, WVb, Wfb);

  // 2) Q/K/V projections + mask pack merged
  k_gemmQKV_pack<<<dim3(1536 + 2048), 256, 0, stream>>>(
      XbQ, XbK, XbV, WQb, WKb, WVb, Qb, Kb, Vt, msk, pbits);

  // 3) fused flash ctx + attn stream (XCD-swizzled linear grid)
  k_flash2<<<dim3(1024), 512, 0, stream>>>(Qb, Kb, Vt, pbits, ctx, out_attn);

  // 4) output projection -> y (f32)
  k_gemmO<<<dim3(Bc * Sc / 128, DMc / 128), 256, 0, stream>>>(ctx, Wfb, y);

  // 5) residual + LayerNorm -> ln (output 0)
  k_ln<<<dim3(Bc * Sc), 256, 0, stream>>>(y, inQ, out_ln);
}